// Round 3
// baseline (234.532 us; speedup 1.0000x reference)
//
#include <hip/hip_runtime.h>
#include <hip/hip_bf16.h>
#include <math.h>

#define V      21841
#define TOPK   250
#define CAP    2048
#define NT     256
#define NWAVE  (NT / 64)

typedef float floatx4 __attribute__((ext_vector_type(4)));

__device__ __forceinline__ float clipf(float v) {
    return fminf(fmaxf(v, -1e15f), 1e15f);
}
// order-preserving float->uint key (ascending uint == ascending float)
__device__ __forceinline__ unsigned int enc(float v) {
    unsigned int b = __float_as_uint(v);
    return (b & 0x80000000u) ? ~b : (b | 0x80000000u);
}
__device__ __forceinline__ float dec(unsigned int k) {
    unsigned int b = (k & 0x80000000u) ? (k & 0x7FFFFFFFu) : ~k;
    return __uint_as_float(b);
}

// wave-aggregated histogram increment: one atomic per DISTINCT bin per wave
// (all lanes of the wave must reach this call together; `valid` masks lanes)
__device__ __forceinline__ void hadd(unsigned int* hist, unsigned int bin, bool valid) {
    unsigned long long todo = __ballot(valid);
    while (todo) {
        int leader = (int)(__ffsll((unsigned long long)todo) - 1);
        unsigned int b = (unsigned int)__shfl((int)bin, leader);
        unsigned long long same = __ballot(valid && (bin == b));
        if ((int)(threadIdx.x & 63) == leader)
            atomicAdd(&hist[b], (unsigned int)__popcll(same));
        todo &= ~same;
    }
}

__global__ __launch_bounds__(NT) void lnclamp_kernel(const float* __restrict__ in,
                                                     float* __restrict__ out) {
    __shared__ unsigned int hist[256];
    __shared__ unsigned int cand[CAP];
    __shared__ int cand_cnt;
    __shared__ unsigned int sh_bin, sh_krem, sh_cnt;
    __shared__ double redS[NWAVE], redS2[NWAVE];
    __shared__ float sh_mean, sh_istd;

    const int row = blockIdx.x;
    const int tid = threadIdx.x;
    const float* rp = in + (size_t)row * V;
    float* op = out + (size_t)row * V;

    // 21841 % 4 == 1, so row start alignment cycles with row & 3
    const int first = (4 - (row & 3)) & 3;   // first 16B-aligned element index
    const int nvec = (V - first) >> 2;
    const int tail = first + (nvec << 2);
    const int niter = (nvec + NT - 1) / NT;
    const float4* vp = reinterpret_cast<const float4*>(rp + first);

    unsigned int prefix = 0, pmask = 0, krem = TOPK;
    bool compacted = false;
    int ncand = 0;
    double s = 0.0, s2 = 0.0;

    for (int level = 0; level < 4; ++level) {
        const int shift = 24 - 8 * level;
        __syncthreads();
        for (int b = tid; b < 256; b += NT) hist[b] = 0;
        __syncthreads();

        if (!compacted) {
            // head (<=3 elements), wave-converged
            {
                bool hv = tid < first;
                float v = hv ? rp[tid] : 0.0f;
                unsigned int k = enc(clipf(v));
                hadd(hist, (k >> shift) & 255u, hv && ((k & pmask) == prefix));
            }
            // vector body, wave-converged (index clamp keeps all lanes in loop)
            for (int it = 0; it < niter; ++it) {
                int j = it * NT + tid;
                bool inb = j < nvec;
                float4 v = vp[inb ? j : 0];
                float vv[4] = {v.x, v.y, v.z, v.w};
#pragma unroll
                for (int q = 0; q < 4; ++q) {
                    unsigned int k = enc(clipf(vv[q]));
                    hadd(hist, (k >> shift) & 255u, inb && ((k & pmask) == prefix));
                }
            }
            // tail (<=3 elements)
            {
                int i = tail + tid;
                bool tv = i < V;
                float v = tv ? rp[tv ? i : 0] : 0.0f;
                unsigned int k = enc(clipf(v));
                hadd(hist, (k >> shift) & 255u, tv && ((k & pmask) == prefix));
            }
        } else {
            // candidates: keys spread over mantissa bits -> low contention, plain atomics
            for (int i = tid; i < ncand; i += NT) {
                unsigned int k = cand[i];
                if ((k & pmask) == prefix) atomicAdd(&hist[(k >> shift) & 255u], 1u);
            }
        }
        __syncthreads();

        if (tid == 0) {
            unsigned int cum = 0;
            int b = 255;
            for (;; --b) {
                cum += hist[b];
                if (cum >= krem || b == 0) break;
            }
            sh_bin = (unsigned int)b;
            sh_krem = krem - (cum - hist[b]);   // still needed inside selected bin
            sh_cnt = hist[b];
            cand_cnt = 0;
        }
        __syncthreads();
        prefix |= sh_bin << shift;
        pmask |= 255u << shift;
        krem = sh_krem;
        const unsigned int m = sh_cnt;

        if (!compacted && m <= CAP) {
            // single fused scan: compact matching keys; sum strictly-greater values
            if (tid < first) {
                float v = clipf(rp[tid]);
                unsigned int k = enc(v), km = k & pmask;
                if (km == prefix) { int p = atomicAdd(&cand_cnt, 1); cand[p] = k; }
                else if (km > prefix) { double dv = v; s += dv; s2 += dv * dv; }
            }
            for (int j = tid; j < nvec; j += NT) {
                float4 v4 = vp[j];
                float vv[4] = {v4.x, v4.y, v4.z, v4.w};
#pragma unroll
                for (int q = 0; q < 4; ++q) {
                    float v = clipf(vv[q]);
                    unsigned int k = enc(v), km = k & pmask;
                    if (km == prefix) { int p = atomicAdd(&cand_cnt, 1); cand[p] = k; }
                    else if (km > prefix) { double dv = v; s += dv; s2 += dv * dv; }
                }
            }
            for (int i = tail + tid; i < V; i += NT) {
                float v = clipf(rp[i]);
                unsigned int k = enc(v), km = k & pmask;
                if (km == prefix) { int p = atomicAdd(&cand_cnt, 1); cand[p] = k; }
                else if (km > prefix) { double dv = v; s += dv; s2 += dv * dv; }
            }
            __syncthreads();
            ncand = cand_cnt;
            compacted = true;
        }
    }

    const unsigned int T = prefix;   // full 32-bit key of the K-th largest

    if (compacted) {
        for (int i = tid; i < ncand; i += NT) {
            unsigned int k = cand[i];
            if (k > T) { double dv = (double)dec(k); s += dv; s2 += dv * dv; }
        }
    } else {
        // fallback (never compacted): sum all strictly-greater from global
        if (tid < first) {
            float v = clipf(rp[tid]);
            if (enc(v) > T) { double dv = v; s += dv; s2 += dv * dv; }
        }
        for (int j = tid; j < nvec; j += NT) {
            float4 v4 = vp[j];
            float vv[4] = {v4.x, v4.y, v4.z, v4.w};
#pragma unroll
            for (int q = 0; q < 4; ++q) {
                float v = clipf(vv[q]);
                if (enc(v) > T) { double dv = v; s += dv; s2 += dv * dv; }
            }
        }
        for (int i = tail + tid; i < V; i += NT) {
            float v = clipf(rp[i]);
            if (enc(v) > T) { double dv = v; s += dv; s2 += dv * dv; }
        }
    }

    // block-reduce s, s2 (wave shuffle then cross-wave via LDS)
    for (int off = 32; off > 0; off >>= 1) {
        s  += __shfl_down(s, off);
        s2 += __shfl_down(s2, off);
    }
    const int wid = tid >> 6, lane = tid & 63;
    if (lane == 0) { redS[wid] = s; redS2[wid] = s2; }
    __syncthreads();
    if (tid == 0) {
        double S = 0.0, S2 = 0.0;
        for (int w = 0; w < NWAVE; ++w) { S += redS[w]; S2 += redS2[w]; }
        const double vT = (double)dec(T);
        S  += (double)krem * vT;
        S2 += (double)krem * vT * vT;
        const double mean = S / (double)TOPK;
        const double var  = (S2 - S * S / (double)TOPK) / (double)(TOPK - 1);
        const double istd = 1.0 / sqrt(var + 1e-8);
        sh_mean = (float)mean;
        sh_istd = (float)istd;
    }
    __syncthreads();
    const float mean = sh_mean, istd = sh_istd;

    // output pass: normed -> exact GELU(n-1) -> *0.4  (POWER=1 => identity)
    // nontemporal stores: output never re-read; keep input resident in L2/L3
    auto outf = [&](float v) -> float {
        float n = (v - mean) * istd - 1.0f;
        float g = 0.5f * n * (1.0f + erff(n * 0.70710678118654752f));
        return g * 0.4f;
    };
    if (tid < first) __builtin_nontemporal_store(outf(clipf(rp[tid])), op + tid);
    floatx4* ovp = reinterpret_cast<floatx4*>(op + first);
    for (int j = tid; j < nvec; j += NT) {
        float4 v4 = vp[j];
        floatx4 o;
        o.x = outf(clipf(v4.x));
        o.y = outf(clipf(v4.y));
        o.z = outf(clipf(v4.z));
        o.w = outf(clipf(v4.w));
        __builtin_nontemporal_store(o, &ovp[j]);
    }
    for (int i = tail + tid; i < V; i += NT)
        __builtin_nontemporal_store(outf(clipf(rp[i])), op + i);
}

extern "C" void kernel_launch(void* const* d_in, const int* in_sizes, int n_in,
                              void* d_out, int out_size, void* d_ws, size_t ws_size,
                              hipStream_t stream) {
    const float* in = (const float*)d_in[0];
    float* out = (float*)d_out;
    const int rows = out_size / V;   // 2048
    hipLaunchKernelGGL(lnclamp_kernel, dim3(rows), dim3(NT), 0, stream, in, out);
}

// Round 4
// 221.171 us; speedup vs baseline: 1.0604x; 1.0604x over previous
//
#include <hip/hip_runtime.h>
#include <math.h>

#define V      21841
#define TOPK   250
#define NT     256
#define NWAVE  (NT / 64)
#define BINS   2048          // 11-bit key bins (sign+exp+2 mantissa bits)
#define BSHIFT 21
#define CAP    3072
#define NSAMP  ((V + 7) / 8)
#define STGT   80u           // sampled cum target (~640 est. full count)
#define SOVR   300u          // overshoot guard (~2400 est.)
#define SMIN   32u           // min sampled count above when stepping up (~256 est.)

__device__ __forceinline__ float clipf(float v) {
    return fminf(fmaxf(v, -1e15f), 1e15f);
}
// order-preserving float->uint key (ascending uint == ascending float)
__device__ __forceinline__ unsigned enc(float v) {
    unsigned b = __float_as_uint(v);
    return (b & 0x80000000u) ? ~b : (b | 0x80000000u);
}
__device__ __forceinline__ float dec(unsigned k) {
    unsigned b = (k & 0x80000000u) ? (k & 0x7FFFFFFFu) : ~k;
    return __uint_as_float(b);
}

__global__ __launch_bounds__(NT) void lnclamp_kernel(const float* __restrict__ in,
                                                     float* __restrict__ out) {
    __shared__ unsigned hist[BINS];
    __shared__ unsigned csum[NT];
    __shared__ unsigned cand[CAP];
    __shared__ int cand_cnt;
    __shared__ unsigned sh_bin, sh_krem;
    __shared__ double redS[NWAVE], redS2[NWAVE];
    __shared__ float sh_mean, sh_istd;

    const int row = blockIdx.x, tid = threadIdx.x, lane = tid & 63;
    const float* rp = in + (size_t)row * V;
    float* op = out + (size_t)row * V;

    // 21841 % 4 == 1 -> 16B alignment phase cycles with row & 3
    const int first = (4 - (row & 3)) & 3;
    const int nvec = (V - first) >> 2;
    const int tail = first + (nvec << 2);
    const int niter = (nvec + NT - 1) / NT;
    const float4* vp = reinterpret_cast<const float4*>(rp + first);

    // ---------- stage 1: sampled (1/8) fine-bin histogram ----------
    for (int b = tid; b < BINS; b += NT) hist[b] = 0;
    __syncthreads();
    for (int j = tid; j < NSAMP; j += NT) {
        unsigned k = enc(clipf(rp[j << 3]));
        atomicAdd(&hist[k >> BSHIFT], 1u);
    }
    __syncthreads();
    {   // per-thread chunk sums (8 bins) for a fast top-down scan
        unsigned ssum = 0;
#pragma unroll
        for (int q = 0; q < 8; ++q) ssum += hist[(tid << 3) + q];
        csum[tid] = ssum;
    }
    __syncthreads();
    if (tid == 0) {
        unsigned cum = 0;
        int c = NT - 1;
        while (c >= 0 && cum + csum[c] < STGT) { cum += csum[c]; --c; }
        int b;
        if (c < 0) { b = 0; cum += hist[0]; }
        else {
            b = (c << 3) + 7;
            while (b > (c << 3) && cum + hist[b] < STGT) { cum += hist[b]; --b; }
            cum += hist[b];
        }
        unsigned above = cum - hist[b];
        if (cum > SOVR && above >= SMIN && b < BINS - 1) { ++b; cum = above; }
        sh_bin = (unsigned)b;
        cand_cnt = 0;
    }
    __syncthreads();
    const unsigned T0 = sh_bin << BSHIFT;
    const float tf = dec(T0);
    const bool kcmp = (T0 & 0x80000000u) == 0;   // non-positive threshold: key compare

    // ---------- stage 2: full scan, ballot-compact keys >= T0 ----------
    auto emit = [&](bool pass, unsigned key) {
        unsigned long long m = __ballot(pass);
        if (m) {
            int ldr = (int)__ffsll(m) - 1;
            int base = 0;
            if (lane == ldr) base = atomicAdd(&cand_cnt, (int)__popcll(m));
            base = __shfl(base, ldr);
            if (pass) {
                int p = base + (int)__popcll(m & ((1ull << lane) - 1ull));
                if (p < CAP) cand[p] = key;
            }
        }
    };
    {   // head (<=3), wave-converged
        bool hv = tid < first;
        float v = rp[hv ? tid : 0];
        unsigned k = enc(clipf(v));
        emit(hv && (kcmp ? (k >= T0) : (v >= tf)), k);
    }
    for (int it = 0; it < niter; ++it) {   // vector body, wave-converged
        int j = it * NT + tid;
        bool inb = j < nvec;
        float4 v4 = vp[inb ? j : 0];
        float vv[4] = {v4.x, v4.y, v4.z, v4.w};
#pragma unroll
        for (int q = 0; q < 4; ++q) {
            float v = vv[q];
            unsigned k = enc(clipf(v));
            emit(inb && (kcmp ? (k >= T0) : (v >= tf)), k);
        }
    }
    {   // tail (<=3), wave-converged
        int i = tail + tid;
        bool tv = i < V;
        float v = rp[tv ? i : 0];
        unsigned k = enc(clipf(v));
        emit(tv && (kcmp ? (k >= T0) : (v >= tf)), k);
    }
    __syncthreads();
    const int ncand = cand_cnt;
    const bool fastok = (ncand >= TOPK) && (ncand <= CAP);

    unsigned T, krem;
    if (fastok) {
        // ---------- stage 3: exact radix over candidates in LDS ----------
        unsigned prefix = 0, pmask = 0, kr = TOPK;
        for (int level = 0; level < 4; ++level) {
            const int shift = 24 - 8 * level;
            __syncthreads();
            if (tid < 256) hist[tid] = 0;
            __syncthreads();
            for (int i = tid; i < ncand; i += NT) {
                unsigned k = cand[i];
                if ((k & pmask) == prefix) atomicAdd(&hist[(k >> shift) & 255u], 1u);
            }
            __syncthreads();
            if (tid == 0) {
                unsigned cum = 0;
                int b = 255;
                for (;; --b) { cum += hist[b]; if (cum >= kr || b == 0) break; }
                sh_bin = (unsigned)b;
                sh_krem = kr - (cum - hist[b]);
            }
            __syncthreads();
            prefix |= sh_bin << shift;
            pmask |= 255u << shift;
            kr = sh_krem;
        }
        T = prefix; krem = kr;

        // stats over candidates (all keys > T live in cand)
        double s = 0.0, s2 = 0.0;
        for (int i = tid; i < ncand; i += NT) {
            unsigned k = cand[i];
            if (k > T) { double dv = (double)dec(k); s += dv; s2 += dv * dv; }
        }
        for (int off = 32; off > 0; off >>= 1) {
            s += __shfl_down(s, off); s2 += __shfl_down(s2, off);
        }
        const int wid = tid >> 6;
        if (lane == 0) { redS[wid] = s; redS2[wid] = s2; }
        __syncthreads();
        if (tid == 0) {
            double S = 0.0, S2 = 0.0;
            for (int w = 0; w < NWAVE; ++w) { S += redS[w]; S2 += redS2[w]; }
            const double vT = (double)dec(T);
            S += (double)krem * vT;
            S2 += (double)krem * vT * vT;
            const double mean = S / (double)TOPK;
            const double var = (S2 - S * S / (double)TOPK) / (double)(TOPK - 1);
            sh_mean = (float)mean;
            sh_istd = (float)(1.0 / sqrt(var + 1e-8));
        }
        __syncthreads();
    } else {
        // ---------- exact fallback: 4-pass MSB radix from global ----------
        unsigned prefix = 0, pmask = 0, kr = TOPK;
        for (int level = 0; level < 4; ++level) {
            const int shift = 24 - 8 * level;
            __syncthreads();
            if (tid < 256) hist[tid] = 0;
            __syncthreads();
            for (int i = tid; i < V; i += NT) {
                unsigned k = enc(clipf(rp[i]));
                if ((k & pmask) == prefix) atomicAdd(&hist[(k >> shift) & 255u], 1u);
            }
            __syncthreads();
            if (tid == 0) {
                unsigned cum = 0;
                int b = 255;
                for (;; --b) { cum += hist[b]; if (cum >= kr || b == 0) break; }
                sh_bin = (unsigned)b;
                sh_krem = kr - (cum - hist[b]);
            }
            __syncthreads();
            prefix |= sh_bin << shift;
            pmask |= 255u << shift;
            kr = sh_krem;
        }
        T = prefix; krem = kr;
        double s = 0.0, s2 = 0.0;
        for (int i = tid; i < V; i += NT) {
            float v = clipf(rp[i]);
            if (enc(v) > T) { double dv = v; s += dv; s2 += dv * dv; }
        }
        for (int off = 32; off > 0; off >>= 1) {
            s += __shfl_down(s, off); s2 += __shfl_down(s2, off);
        }
        const int wid = tid >> 6;
        if (lane == 0) { redS[wid] = s; redS2[wid] = s2; }
        __syncthreads();
        if (tid == 0) {
            double S = 0.0, S2 = 0.0;
            for (int w = 0; w < NWAVE; ++w) { S += redS[w]; S2 += redS2[w]; }
            const double vT = (double)dec(T);
            S += (double)krem * vT;
            S2 += (double)krem * vT * vT;
            const double mean = S / (double)TOPK;
            const double var = (S2 - S * S / (double)TOPK) / (double)(TOPK - 1);
            sh_mean = (float)mean;
            sh_istd = (float)(1.0 / sqrt(var + 1e-8));
        }
        __syncthreads();
    }

    // ---------- stage 4: output pass ----------
    const float istd = sh_istd;
    const float c1 = -sh_mean * istd - 1.0f;   // n = clip(v)*istd + c1
    auto outf = [&](float v) -> float {
        float n = fmaf(clipf(v), istd, c1);
        return n * (1.0f + erff(n * 0.70710678118654752f)) * 0.2f;
    };
    if (tid < first) op[tid] = outf(rp[tid]);
    float4* ovp = reinterpret_cast<float4*>(op + first);
    for (int j = tid; j < nvec; j += NT) {
        float4 v4 = vp[j];
        float4 o;
        o.x = outf(v4.x);
        o.y = outf(v4.y);
        o.z = outf(v4.z);
        o.w = outf(v4.w);
        ovp[j] = o;
    }
    for (int i = tail + tid; i < V; i += NT) op[i] = outf(rp[i]);
}

extern "C" void kernel_launch(void* const* d_in, const int* in_sizes, int n_in,
                              void* d_out, int out_size, void* d_ws, size_t ws_size,
                              hipStream_t stream) {
    const float* in = (const float*)d_in[0];
    float* out = (float*)d_out;
    const int rows = out_size / V;   // 2048
    hipLaunchKernelGGL(lnclamp_kernel, dim3(rows), dim3(NT), 0, stream, in, out);
}

// Round 5
// 188.000 us; speedup vs baseline: 1.2475x; 1.1764x over previous
//
#include <hip/hip_runtime.h>
#include <math.h>

#define V      21841
#define TOPK   250
#define NT     256
#define NWAVE  (NT / 64)
#define BINS   2048          // 11-bit key bins (sign + 8 exp + 2 mantissa bits)
#define BSHIFT 21
#define CAP    2560
#define NSAMP  2730          // contiguous prefix sample, ~V/8
#define STGT   60u           // sampled cum target (est. >=480 full candidates)
#define SHI    240u          // step-up trigger (est. ~1900)
#define SUP    60u           // min sampled count above when stepping up (est. ~480)

__device__ __forceinline__ float clipf(float v) {
    return fminf(fmaxf(v, -1e15f), 1e15f);
}
// order-preserving float->uint key (ascending uint == ascending float)
__device__ __forceinline__ unsigned enc(float v) {
    unsigned b = __float_as_uint(v);
    return (b & 0x80000000u) ? ~b : (b | 0x80000000u);
}
__device__ __forceinline__ float dec(unsigned k) {
    unsigned b = (k & 0x80000000u) ? (k & 0x7FFFFFFFu) : ~k;
    return __uint_as_float(b);
}

__global__ __launch_bounds__(NT) void lnclamp_kernel(const float* __restrict__ in,
                                                     float* __restrict__ out) {
    __shared__ unsigned hist[BINS];
    __shared__ unsigned csum[NT];
    __shared__ unsigned cand[CAP];
    __shared__ int cand_cnt;
    __shared__ unsigned sh_bin, sh_krem;
    __shared__ double redS[NWAVE], redS2[NWAVE];
    __shared__ float sh_mean, sh_istd;

    const int row = blockIdx.x, tid = threadIdx.x, lane = tid & 63;
    const float* rp = in + (size_t)row * V;
    float* op = out + (size_t)row * V;

    // 21841 % 4 == 1 -> 16B alignment phase cycles with row & 3
    const int first = (4 - (row & 3)) & 3;
    const int nvec = (V - first) >> 2;
    const int tail = first + (nvec << 2);
    const float4* vp = reinterpret_cast<const float4*>(rp + first);

    // ---------- stage 1: contiguous-prefix sampled histogram (coalesced) ----------
    for (int b = tid; b < BINS; b += NT) hist[b] = 0;
    if (tid == 0) cand_cnt = 0;
    __syncthreads();
    {
        if (tid < first) atomicAdd(&hist[enc(clipf(rp[tid])) >> BSHIFT], 1u);
        const int svec = (NSAMP - first) >> 2;
        for (int j = tid; j < svec; j += NT) {
            float4 v = vp[j];
            atomicAdd(&hist[enc(clipf(v.x)) >> BSHIFT], 1u);
            atomicAdd(&hist[enc(clipf(v.y)) >> BSHIFT], 1u);
            atomicAdd(&hist[enc(clipf(v.z)) >> BSHIFT], 1u);
            atomicAdd(&hist[enc(clipf(v.w)) >> BSHIFT], 1u);
        }
    }
    __syncthreads();
    {   // per-thread chunk sums (8 bins each) for a fast top-down scan
        unsigned ssum = 0;
#pragma unroll
        for (int q = 0; q < 8; ++q) ssum += hist[(tid << 3) + q];
        csum[tid] = ssum;
    }
    __syncthreads();
    if (tid == 0) {
        unsigned cum = 0;
        int c = NT - 1;
        while (c >= 0 && cum + csum[c] < STGT) { cum += csum[c]; --c; }
        int b = 0;
        if (c >= 0) {
            b = (c << 3) + 7;
            while (b > (c << 3) && cum + hist[b] < STGT) { cum += hist[b]; --b; }
            cum += hist[b];
            // overshoot guard: step up one bin if enough mass remains above
            if (cum > SHI && b < BINS - 1 && (cum - hist[b]) >= SUP) ++b;
        }
        sh_bin = (unsigned)b;
    }
    __syncthreads();
    const unsigned T0 = sh_bin << BSHIFT;
    const float tf = dec(T0);
    const bool fcmp = (T0 > 0x80000000u);   // strictly-positive threshold: plain float compare ok

    // ---------- stage 2: full scan, one compare/element; atomics only on passers ----------
    auto emit = [&](float v) {
        bool pass = fcmp ? (v >= tf) : (enc(clipf(v)) >= T0);
        if (pass) {
            int p = atomicAdd(&cand_cnt, 1);
            if (p < CAP) cand[p] = enc(clipf(v));
        }
    };
    if (tid < first) emit(rp[tid]);
    for (int j = tid; j < nvec; j += NT) {
        float4 v4 = vp[j];
        emit(v4.x); emit(v4.y); emit(v4.z); emit(v4.w);
    }
    for (int i = tail + tid; i < V; i += NT) emit(rp[i]);
    __syncthreads();
    const int ncand = cand_cnt;
    const bool fastok = (ncand >= TOPK) && (ncand <= CAP);

    unsigned T, krem;
    if (fastok) {
        // ---------- stage 3: exact radix over candidates in LDS ----------
        unsigned prefix = 0, pmask = 0, kr = TOPK;
        for (int level = 0; level < 4; ++level) {
            const int shift = 24 - 8 * level;
            __syncthreads();
            if (tid < 256) hist[tid] = 0;
            __syncthreads();
            for (int i = tid; i < ncand; i += NT) {
                unsigned k = cand[i];
                if ((k & pmask) == prefix) atomicAdd(&hist[(k >> shift) & 255u], 1u);
            }
            __syncthreads();
            if (tid == 0) {
                unsigned cum = 0;
                int b = 255;
                for (;; --b) { cum += hist[b]; if (cum >= kr || b == 0) break; }
                sh_bin = (unsigned)b;
                sh_krem = kr - (cum - hist[b]);
            }
            __syncthreads();
            prefix |= sh_bin << shift;
            pmask |= 255u << shift;
            kr = sh_krem;
        }
        T = prefix; krem = kr;

        double s = 0.0, s2 = 0.0;
        for (int i = tid; i < ncand; i += NT) {
            unsigned k = cand[i];
            if (k > T) { double dv = (double)dec(k); s += dv; s2 += dv * dv; }
        }
        for (int off = 32; off > 0; off >>= 1) {
            s += __shfl_down(s, off); s2 += __shfl_down(s2, off);
        }
        const int wid = tid >> 6;
        if (lane == 0) { redS[wid] = s; redS2[wid] = s2; }
        __syncthreads();
        if (tid == 0) {
            double S = 0.0, S2 = 0.0;
            for (int w = 0; w < NWAVE; ++w) { S += redS[w]; S2 += redS2[w]; }
            const double vT = (double)dec(T);
            S += (double)krem * vT;
            S2 += (double)krem * vT * vT;
            const double mean = S / (double)TOPK;
            const double var = (S2 - S * S / (double)TOPK) / (double)(TOPK - 1);
            sh_mean = (float)mean;
            sh_istd = (float)(1.0 / sqrt(var + 1e-8));
        }
        __syncthreads();
    } else {
        // ---------- exact fallback: 4-pass MSB radix from global ----------
        unsigned prefix = 0, pmask = 0, kr = TOPK;
        for (int level = 0; level < 4; ++level) {
            const int shift = 24 - 8 * level;
            __syncthreads();
            if (tid < 256) hist[tid] = 0;
            __syncthreads();
            for (int i = tid; i < V; i += NT) {
                unsigned k = enc(clipf(rp[i]));
                if ((k & pmask) == prefix) atomicAdd(&hist[(k >> shift) & 255u], 1u);
            }
            __syncthreads();
            if (tid == 0) {
                unsigned cum = 0;
                int b = 255;
                for (;; --b) { cum += hist[b]; if (cum >= kr || b == 0) break; }
                sh_bin = (unsigned)b;
                sh_krem = kr - (cum - hist[b]);
            }
            __syncthreads();
            prefix |= sh_bin << shift;
            pmask |= 255u << shift;
            kr = sh_krem;
        }
        T = prefix; krem = kr;
        double s = 0.0, s2 = 0.0;
        for (int i = tid; i < V; i += NT) {
            float v = clipf(rp[i]);
            if (enc(v) > T) { double dv = v; s += dv; s2 += dv * dv; }
        }
        for (int off = 32; off > 0; off >>= 1) {
            s += __shfl_down(s, off); s2 += __shfl_down(s2, off);
        }
        const int wid = tid >> 6;
        if (lane == 0) { redS[wid] = s; redS2[wid] = s2; }
        __syncthreads();
        if (tid == 0) {
            double S = 0.0, S2 = 0.0;
            for (int w = 0; w < NWAVE; ++w) { S += redS[w]; S2 += redS2[w]; }
            const double vT = (double)dec(T);
            S += (double)krem * vT;
            S2 += (double)krem * vT * vT;
            const double mean = S / (double)TOPK;
            const double var = (S2 - S * S / (double)TOPK) / (double)(TOPK - 1);
            sh_mean = (float)mean;
            sh_istd = (float)(1.0 / sqrt(var + 1e-8));
        }
        __syncthreads();
    }

    // ---------- stage 4: output pass ----------
    const float istd = sh_istd;
    const float c1 = -sh_mean * istd - 1.0f;   // n = clip(v)*istd + c1
    auto outf = [&](float v) -> float {
        float n = fmaf(clipf(v), istd, c1);
        return n * (1.0f + erff(n * 0.70710678118654752f)) * 0.2f;
    };
    if (tid < first) op[tid] = outf(rp[tid]);
    float4* ovp = reinterpret_cast<float4*>(op + first);
    for (int j = tid; j < nvec; j += NT) {
        float4 v4 = vp[j];
        float4 o;
        o.x = outf(v4.x);
        o.y = outf(v4.y);
        o.z = outf(v4.z);
        o.w = outf(v4.w);
        ovp[j] = o;
    }
    for (int i = tail + tid; i < V; i += NT) op[i] = outf(rp[i]);
}

extern "C" void kernel_launch(void* const* d_in, const int* in_sizes, int n_in,
                              void* d_out, int out_size, void* d_ws, size_t ws_size,
                              hipStream_t stream) {
    const float* in = (const float*)d_in[0];
    float* out = (float*)d_out;
    const int rows = out_size / V;   // 2048
    hipLaunchKernelGGL(lnclamp_kernel, dim3(rows), dim3(NT), 0, stream, in, out);
}

// Round 6
// 129.360 us; speedup vs baseline: 1.8130x; 1.4533x over previous
//
#include <hip/hip_runtime.h>
#include <math.h>

#define V      21841
#define TOPK   250
#define NT     256
#define NWAVE  (NT / 64)
#define BINS   2048          // 11-bit key bins (sign + 8 exp + 2 mantissa bits)
#define BSHIFT 21
#define CAP    2048
#define NSAMP  2730          // contiguous prefix sample, ~V/8
#define STGT   60u           // sampled cum target (est. >=480 full candidates)
#define SHI    200u          // step-up trigger (est. ~1600 full, +3sigma < CAP)
#define SUP    60u           // min sampled count above when stepping up (est. ~480)

__device__ __forceinline__ float clipf(float v) {
    return fminf(fmaxf(v, -1e15f), 1e15f);
}
// order-preserving float->uint key (ascending uint == ascending float)
__device__ __forceinline__ unsigned enc(float v) {
    unsigned b = __float_as_uint(v);
    return (b & 0x80000000u) ? ~b : (b | 0x80000000u);
}
__device__ __forceinline__ float dec(unsigned k) {
    unsigned b = (k & 0x80000000u) ? (k & 0x7FFFFFFFu) : ~k;
    return __uint_as_float(b);
}

// wave-0 parallel select over a 256-bin LDS histogram:
// finds largest bin b with suffix_sum(b) >= kr; writes bin and krem = kr - suffix_sum(b+1).
// Call with all threads; only tid<64 participates. Caller barriers after.
__device__ __forceinline__ void wave_select256(const unsigned* hist, unsigned kr,
                                               unsigned* sh_bin, unsigned* sh_krem) {
    const int tid = threadIdx.x;
    if (tid < 64) {
        uint4 h = reinterpret_cast<const uint4*>(hist)[tid];
        unsigned lsum = h.x + h.y + h.z + h.w;
        unsigned suf = lsum;
#pragma unroll
        for (int off = 1; off < 64; off <<= 1) {
            unsigned t = __shfl_down(suf, off);
            if (tid + off < 64) suf += t;
        }
        unsigned above = suf - lsum;           // strictly above my 4-bin group
        if (above < kr && suf >= kr) {         // unique crossing lane
            unsigned hb[4] = {h.x, h.y, h.z, h.w};
            unsigned cum = above;
            int q = 3;
            for (; q >= 0; --q) { cum += hb[q]; if (cum >= kr) break; }
            *sh_bin = (unsigned)((tid << 2) + q);
            *sh_krem = kr - (cum - hb[q]);
        }
    }
}

__global__ __launch_bounds__(NT) void lnclamp_kernel(const float* __restrict__ in,
                                                     float* __restrict__ out) {
    __shared__ __align__(16) unsigned hist[BINS];
    __shared__ __align__(16) unsigned cand[CAP];
    __shared__ int cand_cnt;
    __shared__ unsigned sh_bin, sh_krem;
    __shared__ double redS[NWAVE], redS2[NWAVE];
    __shared__ float sh_mean, sh_istd;

    const int row = blockIdx.x, tid = threadIdx.x, lane = tid & 63;
    const float* rp = in + (size_t)row * V;
    float* op = out + (size_t)row * V;

    // 21841 % 4 == 1 -> 16B alignment phase cycles with row & 3
    const int first = (4 - (row & 3)) & 3;
    const int nvec = (V - first) >> 2;
    const int tail = first + (nvec << 2);
    const float4* vp = reinterpret_cast<const float4*>(rp + first);

    // ---------- stage 1: contiguous-prefix sampled histogram (coalesced) ----------
    for (int b = tid; b < BINS; b += NT) hist[b] = 0;
    if (tid == 0) cand_cnt = 0;
    __syncthreads();
    {
        if (tid < first) atomicAdd(&hist[enc(clipf(rp[tid])) >> BSHIFT], 1u);
        const int svec = (NSAMP - first) >> 2;
        for (int j = tid; j < svec; j += NT) {
            float4 v = vp[j];
            atomicAdd(&hist[enc(clipf(v.x)) >> BSHIFT], 1u);
            atomicAdd(&hist[enc(clipf(v.y)) >> BSHIFT], 1u);
            atomicAdd(&hist[enc(clipf(v.z)) >> BSHIFT], 1u);
            atomicAdd(&hist[enc(clipf(v.w)) >> BSHIFT], 1u);
        }
    }
    __syncthreads();
    // wave-0 parallel select over 2048 bins (suffix-scan in registers)
    if (tid < 64) {
        unsigned lsum = 0;
        const uint4* hp = reinterpret_cast<const uint4*>(hist) + (tid << 3);
#pragma unroll
        for (int q = 0; q < 8; ++q) { uint4 h = hp[q]; lsum += h.x + h.y + h.z + h.w; }
        unsigned suf = lsum;
#pragma unroll
        for (int off = 1; off < 64; off <<= 1) {
            unsigned t = __shfl_down(suf, off);
            if (tid + off < 64) suf += t;
        }
        unsigned above = suf - lsum;
        if (above < STGT && suf >= STGT) {     // unique crossing lane
            unsigned cum = above, hb = 0;
            int b = tid << 5;
            for (int q = 31; q >= 0; --q) {
                hb = hist[(tid << 5) + q];
                cum += hb;
                if (cum >= STGT) { b = (tid << 5) + q; break; }
            }
            // overshoot guard: step up one bin if enough mass remains above
            if (cum > SHI && b < BINS - 1 && (cum - hb) >= SUP) ++b;
            sh_bin = (unsigned)b;
        }
    }
    __syncthreads();
    const unsigned T0 = sh_bin << BSHIFT;
    const float tf = dec(T0);
    const bool fcmp = (T0 > 0x80000000u);   // strictly-positive threshold: float compare ok

    // ---------- stage 2: full scan, one compare/element; atomics only on passers ----------
    auto emit = [&](float v) {
        bool pass = fcmp ? (v >= tf) : (enc(clipf(v)) >= T0);
        if (pass) {
            int p = atomicAdd(&cand_cnt, 1);
            if (p < CAP) cand[p] = enc(clipf(v));
        }
    };
    if (tid < first) emit(rp[tid]);
    for (int j = tid; j < nvec; j += NT) {
        float4 v4 = vp[j];
        emit(v4.x); emit(v4.y); emit(v4.z); emit(v4.w);
    }
    for (int i = tail + tid; i < V; i += NT) emit(rp[i]);
    __syncthreads();
    const int ncand = cand_cnt;
    const bool fastok = (ncand >= TOPK) && (ncand <= CAP);

    unsigned T, krem;
    if (fastok) {
        // ---------- stage 3: exact radix over candidates in LDS ----------
        unsigned prefix = 0, pmask = 0, kr = TOPK;
        for (int level = 0; level < 4; ++level) {
            const int shift = 24 - 8 * level;
            __syncthreads();
            if (tid < 256) hist[tid] = 0;
            __syncthreads();
            for (int i = tid; i < ncand; i += NT) {
                unsigned k = cand[i];
                if ((k & pmask) == prefix) atomicAdd(&hist[(k >> shift) & 255u], 1u);
            }
            __syncthreads();
            wave_select256(hist, kr, &sh_bin, &sh_krem);
            __syncthreads();
            prefix |= sh_bin << shift;
            pmask |= 255u << shift;
            kr = sh_krem;
        }
        T = prefix; krem = kr;

        double s = 0.0, s2 = 0.0;
        for (int i = tid; i < ncand; i += NT) {
            unsigned k = cand[i];
            if (k > T) { double dv = (double)dec(k); s += dv; s2 += dv * dv; }
        }
        for (int off = 32; off > 0; off >>= 1) {
            s += __shfl_down(s, off); s2 += __shfl_down(s2, off);
        }
        const int wid = tid >> 6;
        if (lane == 0) { redS[wid] = s; redS2[wid] = s2; }
        __syncthreads();
        if (tid == 0) {
            double S = 0.0, S2 = 0.0;
            for (int w = 0; w < NWAVE; ++w) { S += redS[w]; S2 += redS2[w]; }
            const double vT = (double)dec(T);
            S += (double)krem * vT;
            S2 += (double)krem * vT * vT;
            const double mean = S / (double)TOPK;
            const double var = (S2 - S * S / (double)TOPK) / (double)(TOPK - 1);
            sh_mean = (float)mean;
            sh_istd = (float)(1.0 / sqrt(var + 1e-8));
        }
        __syncthreads();
    } else {
        // ---------- exact fallback: 4-pass MSB radix from global ----------
        unsigned prefix = 0, pmask = 0, kr = TOPK;
        for (int level = 0; level < 4; ++level) {
            const int shift = 24 - 8 * level;
            __syncthreads();
            if (tid < 256) hist[tid] = 0;
            __syncthreads();
            for (int i = tid; i < V; i += NT) {
                unsigned k = enc(clipf(rp[i]));
                if ((k & pmask) == prefix) atomicAdd(&hist[(k >> shift) & 255u], 1u);
            }
            __syncthreads();
            wave_select256(hist, kr, &sh_bin, &sh_krem);
            __syncthreads();
            prefix |= sh_bin << shift;
            pmask |= 255u << shift;
            kr = sh_krem;
        }
        T = prefix; krem = kr;
        double s = 0.0, s2 = 0.0;
        for (int i = tid; i < V; i += NT) {
            float v = clipf(rp[i]);
            if (enc(v) > T) { double dv = v; s += dv; s2 += dv * dv; }
        }
        for (int off = 32; off > 0; off >>= 1) {
            s += __shfl_down(s, off); s2 += __shfl_down(s2, off);
        }
        const int wid = tid >> 6;
        if (lane == 0) { redS[wid] = s; redS2[wid] = s2; }
        __syncthreads();
        if (tid == 0) {
            double S = 0.0, S2 = 0.0;
            for (int w = 0; w < NWAVE; ++w) { S += redS[w]; S2 += redS2[w]; }
            const double vT = (double)dec(T);
            S += (double)krem * vT;
            S2 += (double)krem * vT * vT;
            const double mean = S / (double)TOPK;
            const double var = (S2 - S * S / (double)TOPK) / (double)(TOPK - 1);
            sh_mean = (float)mean;
            sh_istd = (float)(1.0 / sqrt(var + 1e-8));
        }
        __syncthreads();
    }

    // ---------- stage 4: output pass ----------
    const float istd = sh_istd;
    const float c1 = -sh_mean * istd - 1.0f;   // n = clip(v)*istd + c1
    auto outf = [&](float v) -> float {
        float n = fmaf(clipf(v), istd, c1);
        return n * (1.0f + erff(n * 0.70710678118654752f)) * 0.2f;
    };
    if (tid < first) op[tid] = outf(rp[tid]);
    float4* ovp = reinterpret_cast<float4*>(op + first);
    for (int j = tid; j < nvec; j += NT) {
        float4 v4 = vp[j];
        float4 o;
        o.x = outf(v4.x);
        o.y = outf(v4.y);
        o.z = outf(v4.z);
        o.w = outf(v4.w);
        ovp[j] = o;
    }
    for (int i = tail + tid; i < V; i += NT) op[i] = outf(rp[i]);
}

extern "C" void kernel_launch(void* const* d_in, const int* in_sizes, int n_in,
                              void* d_out, int out_size, void* d_ws, size_t ws_size,
                              hipStream_t stream) {
    const float* in = (const float*)d_in[0];
    float* out = (float*)d_out;
    const int rows = out_size / V;   // 2048
    hipLaunchKernelGGL(lnclamp_kernel, dim3(rows), dim3(NT), 0, stream, in, out);
}

// Round 7
// 92.486 us; speedup vs baseline: 2.5359x; 1.3987x over previous
//
#include <hip/hip_runtime.h>
#include <math.h>

#define V      21841
#define TOPK   250
#define NT     256
#define NWAVE  (NT / 64)
#define CAP    2048
#define NCH    6            // chunks per row in map kernel: NCH*1024 >= 5460 float4s
#define TF0    8.0f         // fixed candidate threshold: 250th/21841 of N(0,16) = 9.17 +/- 0.10;
                            // T0=8.0 -> ~497+/-22 candidates. Exact fallback if out of [TOPK, CAP].

typedef float floatx4 __attribute__((ext_vector_type(4)));

__device__ __forceinline__ float clipf(float v) {
    return fminf(fmaxf(v, -1e15f), 1e15f);
}
// order-preserving float->uint key (ascending uint == ascending float)
__device__ __forceinline__ unsigned enc(float v) {
    unsigned b = __float_as_uint(v);
    return (b & 0x80000000u) ? ~b : (b | 0x80000000u);
}
__device__ __forceinline__ float dec(unsigned k) {
    unsigned b = (k & 0x80000000u) ? (k & 0x7FFFFFFFu) : ~k;
    return __uint_as_float(b);
}

// wave-0 parallel select over a 256-bin LDS histogram (suffix-scan in registers):
// finds largest bin b with suffix_sum(b) >= kr; writes bin and krem.
__device__ __forceinline__ void wave_select256(const unsigned* hist, unsigned kr,
                                               unsigned* sh_bin, unsigned* sh_krem) {
    const int tid = threadIdx.x;
    if (tid < 64) {
        uint4 h = reinterpret_cast<const uint4*>(hist)[tid];
        unsigned lsum = h.x + h.y + h.z + h.w;
        unsigned suf = lsum;
#pragma unroll
        for (int off = 1; off < 64; off <<= 1) {
            unsigned t = __shfl_down(suf, off);
            if (tid + off < 64) suf += t;
        }
        unsigned above = suf - lsum;           // strictly above my 4-bin group
        if (above < kr && suf >= kr) {         // unique crossing lane
            unsigned hb[4] = {h.x, h.y, h.z, h.w};
            unsigned cum = above;
            int q = 3;
            for (; q >= 0; --q) { cum += hb[q]; if (cum >= kr) break; }
            *sh_bin = (unsigned)((tid << 2) + q);
            *sh_krem = kr - (cum - hb[q]);
        }
    }
}

// ---------------- K1: per-row top-K stats -> d_ws ----------------
__global__ __launch_bounds__(NT) void stats_kernel(const float* __restrict__ in,
                                                   float2* __restrict__ stats) {
    __shared__ __align__(16) unsigned hist[256];
    __shared__ __align__(16) unsigned cand[CAP];
    __shared__ int cand_cnt;
    __shared__ unsigned sh_bin, sh_krem;
    __shared__ double redS[NWAVE], redS2[NWAVE];

    const int row = blockIdx.x, tid = threadIdx.x, lane = tid & 63;
    const float* rp = in + (size_t)row * V;

    const int first = (4 - (row & 3)) & 3;   // 16B alignment phase (V % 4 == 1)
    const int nvec = (V - first) >> 2;
    const int tail = first + (nvec << 2);
    const float4* vp = reinterpret_cast<const float4*>(rp + first);

    if (tid == 0) cand_cnt = 0;
    __syncthreads();

    // full scan: one float-compare per element; atomics only on ~2.3% passers
    auto emit = [&](float v) {
        if (v >= TF0) {
            int p = atomicAdd(&cand_cnt, 1);
            if (p < CAP) cand[p] = enc(clipf(v));
        }
    };
    if (tid < first) emit(rp[tid]);
    for (int j = tid; j < nvec; j += NT) {
        float4 v4 = vp[j];
        emit(v4.x); emit(v4.y); emit(v4.z); emit(v4.w);
    }
    for (int i = tail + tid; i < V; i += NT) emit(rp[i]);
    __syncthreads();
    const int ncand = cand_cnt;
    const bool fastok = (ncand >= TOPK) && (ncand <= CAP);

    unsigned T, krem;
    double s = 0.0, s2 = 0.0;
    if (fastok) {
        // exact radix over candidates in LDS
        unsigned prefix = 0, pmask = 0, kr = TOPK;
        for (int level = 0; level < 4; ++level) {
            const int shift = 24 - 8 * level;
            __syncthreads();
            hist[tid] = 0;
            __syncthreads();
            for (int i = tid; i < ncand; i += NT) {
                unsigned k = cand[i];
                if ((k & pmask) == prefix) atomicAdd(&hist[(k >> shift) & 255u], 1u);
            }
            __syncthreads();
            wave_select256(hist, kr, &sh_bin, &sh_krem);
            __syncthreads();
            prefix |= sh_bin << shift;
            pmask |= 255u << shift;
            kr = sh_krem;
        }
        T = prefix; krem = kr;
        for (int i = tid; i < ncand; i += NT) {
            unsigned k = cand[i];
            if (k > T) { double dv = (double)dec(k); s += dv; s2 += dv * dv; }
        }
    } else {
        // exact fallback: 4-pass MSB radix from global (any data distribution)
        unsigned prefix = 0, pmask = 0, kr = TOPK;
        for (int level = 0; level < 4; ++level) {
            const int shift = 24 - 8 * level;
            __syncthreads();
            hist[tid] = 0;
            __syncthreads();
            for (int i = tid; i < V; i += NT) {
                unsigned k = enc(clipf(rp[i]));
                if ((k & pmask) == prefix) atomicAdd(&hist[(k >> shift) & 255u], 1u);
            }
            __syncthreads();
            wave_select256(hist, kr, &sh_bin, &sh_krem);
            __syncthreads();
            prefix |= sh_bin << shift;
            pmask |= 255u << shift;
            kr = sh_krem;
        }
        T = prefix; krem = kr;
        for (int i = tid; i < V; i += NT) {
            float v = clipf(rp[i]);
            if (enc(v) > T) { double dv = v; s += dv; s2 += dv * dv; }
        }
    }

    // block-reduce s, s2
    for (int off = 32; off > 0; off >>= 1) {
        s += __shfl_down(s, off); s2 += __shfl_down(s2, off);
    }
    const int wid = tid >> 6;
    if (lane == 0) { redS[wid] = s; redS2[wid] = s2; }
    __syncthreads();
    if (tid == 0) {
        double S = 0.0, S2 = 0.0;
        for (int w = 0; w < NWAVE; ++w) { S += redS[w]; S2 += redS2[w]; }
        const double vT = (double)dec(T);
        S += (double)krem * vT;
        S2 += (double)krem * vT * vT;
        const double mean = S / (double)TOPK;
        const double var = (S2 - S * S / (double)TOPK) / (double)(TOPK - 1);
        stats[row] = make_float2((float)mean, (float)(1.0 / sqrt(var + 1e-8)));
    }
}

// ---------------- K2: pure streaming elementwise map ----------------
__global__ __launch_bounds__(NT) void map_kernel(const float* __restrict__ in,
                                                 const float2* __restrict__ stats,
                                                 float* __restrict__ out) {
    const int row = blockIdx.y, c = blockIdx.x, tid = threadIdx.x;
    const float* rp = in + (size_t)row * V;
    float* op = out + (size_t)row * V;
    const float2 ms = stats[row];
    const float istd = ms.y;
    const float c1 = -ms.x * istd - 1.0f;     // n = clip(v)*istd + c1

    // GELU tanh-form via exp: g = n*(1-r), r = 1/(1+exp(1.5957691*(n+0.044715*n^3)))
    auto outf = [&](float v) -> float {
        float n = fmaf(clipf(v), istd, c1);
        float t1 = n * n;
        float t3 = fmaf(t1 * n, 0.044715f, n);
        float e = __expf(1.59576912160573f * t3);
        float r = __frcp_rn(1.0f + e);          // 1/(1+e^y) = (1-tanh(y/2))/2
        float w = fmaf(-0.4f, r, 0.4f);         // 0.4*(1-r)
        return n * w;
    };

    const int first = (4 - (row & 3)) & 3;
    const int nvec = (V - first) >> 2;
    const float4* vp = reinterpret_cast<const float4*>(rp + first);
    floatx4* ovp = reinterpret_cast<floatx4*>(op + first);

    if (c == 0 && tid < first) op[tid] = outf(rp[tid]);
    if (c == NCH - 1) {
        const int tail = first + (nvec << 2);
        int i = tail + tid;
        if (i < V) op[i] = outf(rp[i]);
    }
    const int base = c * (NT * 4) + tid;
#pragma unroll
    for (int q = 0; q < 4; ++q) {
        int j = base + q * NT;
        if (j < nvec) {
            float4 v4 = vp[j];
            floatx4 o;
            o.x = outf(v4.x);
            o.y = outf(v4.y);
            o.z = outf(v4.z);
            o.w = outf(v4.w);
            __builtin_nontemporal_store(o, &ovp[j]);
        }
    }
}

extern "C" void kernel_launch(void* const* d_in, const int* in_sizes, int n_in,
                              void* d_out, int out_size, void* d_ws, size_t ws_size,
                              hipStream_t stream) {
    const float* in = (const float*)d_in[0];
    float* out = (float*)d_out;
    float2* stats = (float2*)d_ws;
    const int rows = out_size / V;   // 2048
    hipLaunchKernelGGL(stats_kernel, dim3(rows), dim3(NT), 0, stream, in, stats);
    hipLaunchKernelGGL(map_kernel, dim3(NCH, rows), dim3(NT), 0, stream, in, stats, out);
}